// Round 10
// baseline (299.717 us; speedup 1.0000x reference)
//
#include <hip/hip_runtime.h>
#include <cstdint>
#include <cstddef>

typedef uint16_t u16;
typedef uint32_t u32;
using f32x4 = __attribute__((ext_vector_type(4))) float;
using s16x8 = __attribute__((ext_vector_type(8))) short;

#define MFMA(a, b, c) __builtin_amdgcn_mfma_f32_16x16x32_bf16((a), (b), (c), 0, 0, 0)

// XOR swizzle for [R][64] bf16 LDS tiles (u16 index units): keeps 16B blocks
// intact, spreads rows across bank slots -> conflict-free b128 access.
#define SWZ(r, c) ((((r) * 64) + (c)) ^ (((r) & 7) << 3))

__device__ __forceinline__ u16 f2bf(float f) {
  u32 u = __builtin_bit_cast(u32, f);
  u += 0x7FFFu + ((u >> 16) & 1u);
  return (u16)(u >> 16);
}
__device__ __forceinline__ float bf2f(u16 h) {
  u32 u = ((u32)h) << 16;
  return __builtin_bit_cast(float, u);
}

// Async global->LDS, 16B per lane. LDS dest = wave-uniform base + lane*16.
__device__ __forceinline__ void gload16(const void* g, void* l) {
  __builtin_amdgcn_global_load_lds(
      (const __attribute__((address_space(1))) void*)g,
      (__attribute__((address_space(3))) void*)l, 16, 0, 0);
}

// ---------------------------------------------------------------------------
// Split fp32 -> bf16 hi + bf16 lo (residual), 8 elements/thread.
// ---------------------------------------------------------------------------
__global__ void split8(const float* __restrict__ in, u16* __restrict__ hi,
                       u16* __restrict__ lo, int n8) {
  int i = blockIdx.x * 256 + threadIdx.x;
  if (i >= n8) return;
  const float4* p4 = (const float4*)in;
  float4 a = p4[2 * i], b = p4[2 * i + 1];
  float v[8] = {a.x, a.y, a.z, a.w, b.x, b.y, b.z, b.w};
  u32 hw[4], lw[4];
#pragma unroll
  for (int j = 0; j < 4; ++j) {
    u16 h0 = f2bf(v[2 * j]), h1 = f2bf(v[2 * j + 1]);
    u16 l0 = f2bf(v[2 * j] - bf2f(h0)), l1 = f2bf(v[2 * j + 1] - bf2f(h1));
    hw[j] = (u32)h0 | ((u32)h1 << 16);
    lw[j] = (u32)l0 | ((u32)l1 << 16);
  }
  ((uint4*)hi)[i] = make_uint4(hw[0], hw[1], hw[2], hw[3]);
  ((uint4*)lo)[i] = make_uint4(lw[0], lw[1], lw[2], lw[3]);
}

// ---------------------------------------------------------------------------
// Split + transpose: in [K][N] fp32 -> out_h/out_l [N][K] bf16.
// ---------------------------------------------------------------------------
__global__ void splitT(const float* __restrict__ in, u16* __restrict__ th,
                       u16* __restrict__ tl, int K, int N) {
  __shared__ float t[32][33];
  const int n0 = blockIdx.x * 32, k0 = blockIdx.y * 32;
  const int tx = threadIdx.x, ty = threadIdx.y;
#pragma unroll
  for (int q = 0; q < 4; ++q)
    t[ty + 8 * q][tx] = in[(size_t)(k0 + ty + 8 * q) * N + n0 + tx];
  __syncthreads();
#pragma unroll
  for (int q = 0; q < 4; ++q) {
    float v = t[tx][ty + 8 * q];
    u16 h = f2bf(v);
    size_t oi = (size_t)(n0 + ty + 8 * q) * K + k0 + tx;
    th[oi] = h;
    tl[oi] = f2bf(v - bf2f(h));
  }
}

// ---------------------------------------------------------------------------
// Coalesced V transpose: qkv V block [N][DH] -> vT [(b,h,d)][N] per head.
// ---------------------------------------------------------------------------
__global__ __launch_bounds__(256) void vtrans(const u16* __restrict__ qkvh,
                                              const u16* __restrict__ qkvl,
                                              u16* __restrict__ vth,
                                              u16* __restrict__ vtl) {
  __shared__ u16 th[4096], tl[4096];
  const int tid = threadIdx.x;
  const int kv0 = blockIdx.x * 64;
  const int hh = blockIdx.y, bb = blockIdx.z;
  const int sc8 = tid & 7, srow = tid >> 3;  // srow 0..31
#pragma unroll
  for (int q = 0; q < 2; ++q) {
    int row = q * 32 + srow;
    size_t ga = (size_t)(bb * 2048 + kv0 + row) * 2304 + 1536 + hh * 64 + sc8 * 8;
    *(uint4*)&th[SWZ(row, sc8 * 8)] = *(const uint4*)(qkvh + ga);
    *(uint4*)&tl[SWZ(row, sc8 * 8)] = *(const uint4*)(qkvl + ga);
  }
  __syncthreads();
#pragma unroll
  for (int q = 0; q < 2; ++q) {
    int d = q * 32 + srow;  // output row = head dim
    u32 hw[4], lw[4];
#pragma unroll
    for (int j = 0; j < 4; ++j) {
      int kv = sc8 * 8 + 2 * j;
      u16 h0 = th[SWZ(kv, d)], h1 = th[SWZ(kv + 1, d)];
      u16 l0 = tl[SWZ(kv, d)], l1 = tl[SWZ(kv + 1, d)];
      hw[j] = (u32)h0 | ((u32)h1 << 16);
      lw[j] = (u32)l0 | ((u32)l1 << 16);
    }
    size_t go = (size_t)((bb * 12 + hh) * 64 + d) * 2048 + kv0 + sc8 * 8;
    *(uint4*)(vth + go) = make_uint4(hw[0], hw[1], hw[2], hw[3]);
    *(uint4*)(vtl + go) = make_uint4(lw[0], lw[1], lw[2], lw[3]);
  }
}

// ---------------------------------------------------------------------------
// Split-bf16 GEMM v2: C[M,N] = A[M,K] @ B[K,N], B given TRANSPOSED [N][K].
// 3-product MFMA (hh + hl + lh). 128x128 tile, BK=32, 256 threads = 4 waves.
// Staging via global_load_lds (16B/lane, LDS dest linear = base + lane*16):
// 4 streams x 2 halves = 8 issues/wave/K-step, no VGPR round-trip.
// Bank-conflict fix: XOR chunk-swizzle on the GLOBAL source address
// (chunk ^= (row>>1)&3), inverted on ds_read -> 2-way max (free).
// MODE 0: write bf16 hi/lo pair. MODE 1: write fp32 + bias.
// ---------------------------------------------------------------------------
template <int MODE>
__global__ __launch_bounds__(256, 3) void gemm_split(
    const u16* __restrict__ Ah, const u16* __restrict__ Al,
    const u16* __restrict__ BTh, const u16* __restrict__ BTl,
    u16* __restrict__ Ch, u16* __restrict__ Cl,
    float* __restrict__ Cf, const float* __restrict__ bias,
    int N, int K) {
  __shared__ u16 Ash[128 * 32], Asl[128 * 32], Bsh[128 * 32], Bsl[128 * 32];

  const int tid = threadIdx.x;
  const int wave = tid >> 6, lane = tid & 63;
  const int lr = lane & 15, lg = lane >> 4;
  const int wm = (wave >> 1) * 64, wn = (wave & 1) * 64;
  const int m0 = blockIdx.y * 128, n0 = blockIdx.x * 128;

  // Staging geometry: wave w covers rows [w*16, w*16+16) and +64 of each
  // 128x32 tile. Lane l -> row w*16 + (l>>2), LDS slot l&3; global chunk
  // (l&3) ^ f(row), f(row) = (row>>1)&3. (+64 preserves f: 64/2 = 32 ≡ 0 mod 4.)
  const int srow = wave * 16 + (lane >> 2);          // 0..63
  const int gc = ((lane & 3) ^ ((srow >> 1) & 3)) * 8;  // swizzled chunk (u16)

  const u16* gAh0 = Ah + (size_t)(m0 + srow) * K + gc;
  const u16* gAl0 = Al + (size_t)(m0 + srow) * K + gc;
  const u16* gBh0 = BTh + (size_t)(n0 + srow) * K + gc;
  const u16* gBl0 = BTl + (size_t)(n0 + srow) * K + gc;
  const size_t rstep = (size_t)64 * K;

  u16* lAh = &Ash[wave * 512];  // wave-uniform LDS bases (16 rows * 32 u16)
  u16* lAl = &Asl[wave * 512];
  u16* lBh = &Bsh[wave * 512];
  u16* lBl = &Bsl[wave * 512];

  const f32x4 fz = {0.f, 0.f, 0.f, 0.f};
  f32x4 acc[4][4];
#pragma unroll
  for (int i = 0; i < 4; ++i)
#pragma unroll
    for (int j = 0; j < 4; ++j) acc[i][j] = fz;

  for (int k0 = 0; k0 < K; k0 += 32) {
    __syncthreads();  // previous iteration's ds_reads done before overwrite
    gload16(gAh0 + k0, lAh);
    gload16(gAh0 + rstep + k0, lAh + 2048);
    gload16(gAl0 + k0, lAl);
    gload16(gAl0 + rstep + k0, lAl + 2048);
    gload16(gBh0 + k0, lBh);
    gload16(gBh0 + rstep + k0, lBh + 2048);
    gload16(gBl0 + k0, lBl);
    gload16(gBl0 + rstep + k0, lBl + 2048);
    __syncthreads();  // compiler drains vmcnt before the barrier

    s16x8 a_h[4], a_l[4];
#pragma unroll
    for (int i = 0; i < 4; ++i) {
      const int ar = wm + i * 16 + lr;
      const int ao = ar * 32 + ((lg ^ ((ar >> 1) & 3)) * 8);
      a_h[i] = *(const s16x8*)&Ash[ao];
      a_l[i] = *(const s16x8*)&Asl[ao];
    }
    __builtin_amdgcn_s_setprio(1);
#pragma unroll
    for (int j = 0; j < 4; ++j) {
      const int br = wn + j * 16 + lr;
      const int bo = br * 32 + ((lg ^ ((br >> 1) & 3)) * 8);
      s16x8 b_h = *(const s16x8*)&Bsh[bo];
      s16x8 b_l = *(const s16x8*)&Bsl[bo];
#pragma unroll
      for (int i = 0; i < 4; ++i) {
        acc[i][j] = MFMA(a_h[i], b_h, acc[i][j]);
        acc[i][j] = MFMA(a_h[i], b_l, acc[i][j]);
        acc[i][j] = MFMA(a_l[i], b_h, acc[i][j]);
      }
    }
    __builtin_amdgcn_s_setprio(0);
  }

#pragma unroll
  for (int i = 0; i < 4; ++i)
#pragma unroll
    for (int r = 0; r < 4; ++r) {
      const int row = m0 + wm + i * 16 + lg * 4 + r;
#pragma unroll
      for (int j = 0; j < 4; ++j) {
        const int col = n0 + wn + j * 16 + lr;
        const float v = acc[i][j][r];
        if constexpr (MODE == 0) {
          u16 hh = f2bf(v);
          Ch[(size_t)row * N + col] = hh;
          Cl[(size_t)row * N + col] = f2bf(v - bf2f(hh));
        } else {
          Cf[(size_t)row * N + col] = v + bias[col];
        }
      }
    }
}

// ---------------------------------------------------------------------------
// Flash attention v4: KV-split=2. 512 threads = 8 waves, 128 q-rows/block,
// each block covers ONE KV half (1024 kv, 16 chunks of 64). Static-max
// softmax P = exp2(s*SC2 - M2) (fixed m; offset cancels after o/l norm) ->
// partials combine by pure addition. Block writes fp32 o-partial + psum-
// partial; combine kernel finishes. Grid: both halves of a (b,h) on the
// same XCD (K/V L2 reuse). LDS 48KB -> 3 blocks/CU = 24 waves/CU.
// ---------------------------------------------------------------------------
__global__ __launch_bounds__(512, 4) void attn_split(
    const u16* __restrict__ qkvh, const u16* __restrict__ qkvl,
    const u16* __restrict__ vth, const u16* __restrict__ vtl,
    float* __restrict__ oP0, float* __restrict__ oP1,
    float* __restrict__ ps) {
  __shared__ u16 Ksh[4096], Ksl[4096], Vsh[4096], Vsl[4096];
  __shared__ u16 Ph[8][1024];

  const int tid = threadIdx.x;
  const int wave = tid >> 6, lane = tid & 63;
  const int lr = lane & 15, lg = lane >> 4;

  // Grid decode: wgid = xcd + 8*(hf + 2*(qb + 16*g)), bh = g*8 + xcd.
  const int wgid = blockIdx.x;
  const int xcd = wgid & 7, t = wgid >> 3;
  const int hf = t & 1, qb = (t >> 1) & 15, g = t >> 5;
  const int bh = g * 8 + xcd;
  const int hh = bh % 12, bb = bh / 12;
  const int q0 = qb * 128;
  const int kbase = hf * 1024;
  const int sc8 = tid & 7, srow = tid >> 3;  // srow 0..63

  constexpr float SC2 = 0.18033688011f;  // 0.125 * log2(e)
  constexpr float M2 = 11.5415603267f;   // 8 * log2(e)

  // ---- Q fragments: direct global load (one-time, per-wave rows) ----
  s16x8 Qh[2], Ql[2];
  {
    const size_t qrow = (size_t)(bb * 2048 + q0 + wave * 16 + lr);
    const u16* qp = qkvh + qrow * 2304 + hh * 64;
    const u16* ql_ = qkvl + qrow * 2304 + hh * 64;
#pragma unroll
    for (int ks = 0; ks < 2; ++ks) {
      Qh[ks] = *(const s16x8*)(qp + ks * 32 + lg * 8);
      Ql[ks] = *(const s16x8*)(ql_ + ks * 32 + lg * 8);
    }
  }

  const f32x4 fz = {0.f, 0.f, 0.f, 0.f};
  f32x4 o[4] = {fz, fz, fz, fz};
  float psum[4] = {0.f, 0.f, 0.f, 0.f};

  uint4 kh, kl, vh, vl;
  auto loadc = [&](int kc) {
    const size_t gk = (size_t)(bb * 2048 + kc + srow) * 2304 + 768 + hh * 64 + sc8 * 8;
    const size_t gv = (size_t)((bb * 12 + hh) * 64 + srow) * 2048 + kc + sc8 * 8;
    kh = *(const uint4*)(qkvh + gk);
    kl = *(const uint4*)(qkvl + gk);
    vh = *(const uint4*)(vth + gv);
    vl = *(const uint4*)(vtl + gv);
  };
  loadc(kbase);

  for (int kc = kbase; kc < kbase + 1024; kc += 64) {
    __syncthreads();  // previous chunk's LDS readers done
    {
      const int li = SWZ(srow, sc8 * 8);
      *(uint4*)&Ksh[li] = kh;
      *(uint4*)&Ksl[li] = kl;
      *(uint4*)&Vsh[li] = vh;
      *(uint4*)&Vsl[li] = vl;
    }
    __syncthreads();
    if (kc + 64 < kbase + 1024) loadc(kc + 64);  // prefetch hides under compute

    // S = Q K^T : s[f] holds q-rows lg*4+r, kv-cols f*16+lr (unscaled)
    f32x4 s[4];
    __builtin_amdgcn_s_setprio(1);
#pragma unroll
    for (int f = 0; f < 4; ++f) {
      s[f] = fz;
#pragma unroll
      for (int ks = 0; ks < 2; ++ks) {
        s16x8 kbh = *(const s16x8*)&Ksh[SWZ(f * 16 + lr, ks * 32 + lg * 8)];
        s16x8 kbl = *(const s16x8*)&Ksl[SWZ(f * 16 + lr, ks * 32 + lg * 8)];
        s[f] = MFMA(Qh[ks], kbh, s[f]);
        s[f] = MFMA(Qh[ks], kbl, s[f]);
        s[f] = MFMA(Ql[ks], kbh, s[f]);
      }
    }
    __builtin_amdgcn_s_setprio(0);

    // P = exp2(s*SC2 - M2); accumulate per-lane row sum from rounded P.
#pragma unroll
    for (int f = 0; f < 4; ++f)
#pragma unroll
      for (int r = 0; r < 4; ++r) {
        float pv = exp2f(fmaf(s[f][r], SC2, -M2));
        u16 p_h = f2bf(pv);
        psum[r] += bf2f(p_h);
        Ph[wave][SWZ(lg * 4 + r, f * 16 + lr)] = p_h;
      }

    // O += P @ (Vh + Vl)
    s16x8 pah[2];
#pragma unroll
    for (int ks = 0; ks < 2; ++ks)
      pah[ks] = *(const s16x8*)&Ph[wave][SWZ(lr, ks * 32 + lg * 8)];
    __builtin_amdgcn_s_setprio(1);
#pragma unroll
    for (int nf = 0; nf < 4; ++nf) {
#pragma unroll
      for (int ks = 0; ks < 2; ++ks) {
        s16x8 vbh = *(const s16x8*)&Vsh[SWZ(nf * 16 + lr, ks * 32 + lg * 8)];
        s16x8 vbl = *(const s16x8*)&Vsl[SWZ(nf * 16 + lr, ks * 32 + lg * 8)];
        o[nf] = MFMA(pah[ks], vbh, o[nf]);
        o[nf] = MFMA(pah[ks], vbl, o[nf]);
      }
    }
    __builtin_amdgcn_s_setprio(0);
  }

  // Row-sum reduction over the 16 kv-col lanes (once per block).
#pragma unroll
  for (int msk = 1; msk < 16; msk <<= 1)
#pragma unroll
    for (int r = 0; r < 4; ++r)
      psum[r] += __shfl_xor(psum[r], msk, 64);

  float* op = hf ? oP1 : oP0;
#pragma unroll
  for (int r = 0; r < 4; ++r) {
    const int row = bb * 2048 + q0 + wave * 16 + lg * 4 + r;
#pragma unroll
    for (int nf = 0; nf < 4; ++nf)
      op[(size_t)row * 768 + hh * 64 + nf * 16 + lr] = o[nf][r];
  }
  if (lr == 0) {
#pragma unroll
    for (int r = 0; r < 4; ++r)
      ps[hf * 49152 + bh * 2048 + q0 + wave * 16 + lg * 4 + r] = psum[r];
  }
}

// ---------------------------------------------------------------------------
// Combine: ao = (o0 + o1) * gate / (p0 + p1), written as bf16 hi/lo pair.
// 8 cols per thread (all within one head since 8 | 64).
// ---------------------------------------------------------------------------
__global__ __launch_bounds__(256) void combine(
    const float* __restrict__ o0, const float* __restrict__ o1,
    const float* __restrict__ ps, const float* __restrict__ gate,
    u16* __restrict__ aoh, u16* __restrict__ aol) {
  const int i = blockIdx.x * 256 + threadIdx.x;
  if (i >= 4096 * 768 / 8) return;
  const int base = i * 8;
  const int row = base / 768, c0 = base % 768;
  const int hh = c0 >> 6;
  const int bb = row >> 11, n = row & 2047;
  const int bh = bb * 12 + hh;
  const float p = ps[bh * 2048 + n] + ps[49152 + bh * 2048 + n];
  const float inv = gate[hh] / p;
  float4 a0 = *(const float4*)(o0 + base);
  float4 a1 = *(const float4*)(o0 + base + 4);
  float4 b0 = *(const float4*)(o1 + base);
  float4 b1 = *(const float4*)(o1 + base + 4);
  float v[8] = {(a0.x + b0.x) * inv, (a0.y + b0.y) * inv,
                (a0.z + b0.z) * inv, (a0.w + b0.w) * inv,
                (a1.x + b1.x) * inv, (a1.y + b1.y) * inv,
                (a1.z + b1.z) * inv, (a1.w + b1.w) * inv};
  u32 hw[4], lw[4];
#pragma unroll
  for (int j = 0; j < 4; ++j) {
    u16 h0 = f2bf(v[2 * j]), h1 = f2bf(v[2 * j + 1]);
    u16 l0 = f2bf(v[2 * j] - bf2f(h0)), l1 = f2bf(v[2 * j + 1] - bf2f(h1));
    hw[j] = (u32)h0 | ((u32)h1 << 16);
    lw[j] = (u32)l0 | ((u32)l1 << 16);
  }
  *(uint4*)(aoh + base) = make_uint4(hw[0], hw[1], hw[2], hw[3]);
  *(uint4*)(aol + base) = make_uint4(lw[0], lw[1], lw[2], lw[3]);
}

// ---------------------------------------------------------------------------
extern "C" void kernel_launch(void* const* d_in, const int* in_sizes, int n_in,
                              void* d_out, int out_size, void* d_ws, size_t ws_size,
                              hipStream_t stream) {
  const float* x = (const float*)d_in[0];
  const float* w_qkv = (const float*)d_in[1];
  const float* gate = (const float*)d_in[2];
  const float* w_proj = (const float*)d_in[3];
  const float* b_proj = (const float*)d_in[4];
  float* out = (float*)d_out;

  u16* p = (u16*)d_ws;
  u16* xh = p; p += (size_t)4096 * 768;
  u16* xl = p; p += (size_t)4096 * 768;
  u16* wqh = p; p += (size_t)2304 * 768;
  u16* wql = p; p += (size_t)2304 * 768;
  u16* wph = p; p += (size_t)768 * 768;
  u16* wpl = p; p += (size_t)768 * 768;
  u16* qh = p; p += (size_t)4096 * 2304;
  u16* ql = p; p += (size_t)4096 * 2304;
  u16* vth = p; p += (size_t)24 * 64 * 2048;
  u16* vtl = p; p += (size_t)24 * 64 * 2048;
  u16* aoh = p; p += (size_t)4096 * 768;
  u16* aol = p; p += (size_t)4096 * 768;
  float* oP1 = (float*)p;  p += (size_t)2 * 4096 * 768;  // 3.1M f32 (new)
  // Reused regions (dead by the time attn runs):
  float* oP0 = (float*)xh;   // 3.1M f32 over xh+xl (12.6MB)
  float* ps  = (float*)wqh;  // 98K f32 over wqh (0.4MB)

  split8<<<dim3(4096 * 768 / 8 / 256), dim3(256), 0, stream>>>(x, xh, xl, 4096 * 768 / 8);
  splitT<<<dim3(2304 / 32, 768 / 32), dim3(32, 8), 0, stream>>>(w_qkv, wqh, wql, 768, 2304);
  splitT<<<dim3(768 / 32, 768 / 32), dim3(32, 8), 0, stream>>>(w_proj, wph, wpl, 768, 768);

  gemm_split<0><<<dim3(2304 / 128, 4096 / 128), dim3(256), 0, stream>>>(
      xh, xl, wqh, wql, qh, ql, nullptr, nullptr, 2304, 768);

  vtrans<<<dim3(32, 12, 2), dim3(256), 0, stream>>>(qh, ql, vth, vtl);

  attn_split<<<dim3(768), dim3(512), 0, stream>>>(qh, ql, vth, vtl, oP0, oP1, ps);

  combine<<<dim3(4096 * 768 / 8 / 256), dim3(256), 0, stream>>>(
      oP0, oP1, ps, gate, aoh, aol);

  gemm_split<1><<<dim3(768 / 128, 4096 / 128), dim3(256), 0, stream>>>(
      aoh, aol, wph, wpl, nullptr, nullptr, out, b_proj, 768, 768);
}

// Round 11
// 285.037 us; speedup vs baseline: 1.0515x; 1.0515x over previous
//
#include <hip/hip_runtime.h>
#include <cstdint>
#include <cstddef>

typedef uint16_t u16;
typedef uint32_t u32;
using f32x4 = __attribute__((ext_vector_type(4))) float;
using s16x8 = __attribute__((ext_vector_type(8))) short;

#define MFMA(a, b, c) __builtin_amdgcn_mfma_f32_16x16x32_bf16((a), (b), (c), 0, 0, 0)

// XOR swizzle for [R][64] bf16 LDS tiles (u16 index units): keeps 16B blocks
// intact, spreads rows across bank slots -> conflict-free b128 access.
#define SWZ(r, c) ((((r) * 64) + (c)) ^ (((r) & 7) << 3))

__device__ __forceinline__ u16 f2bf(float f) {
  u32 u = __builtin_bit_cast(u32, f);
  u += 0x7FFFu + ((u >> 16) & 1u);
  return (u16)(u >> 16);
}
__device__ __forceinline__ float bf2f(u16 h) {
  u32 u = ((u32)h) << 16;
  return __builtin_bit_cast(float, u);
}

// Async global->LDS, 16B per lane. LDS dest = wave-uniform base + lane*16.
__device__ __forceinline__ void gload16(const void* g, void* l) {
  __builtin_amdgcn_global_load_lds(
      (const __attribute__((address_space(1))) void*)g,
      (__attribute__((address_space(3))) void*)l, 16, 0, 0);
}

// ---------------------------------------------------------------------------
// prep: fused {split8 over x} + {splitT over w_qkv} + {splitT over w_proj}.
// One dispatch, whole-block branching (no divergence). Saves 2 launch gaps.
// Block layout: [0,1536) split8, [1536,3264) splitT w_qkv, [3264,3840) w_proj.
// ---------------------------------------------------------------------------
__global__ __launch_bounds__(256) void prep(
    const float* __restrict__ x, u16* __restrict__ xh, u16* __restrict__ xl,
    const float* __restrict__ w_qkv, u16* __restrict__ wqh, u16* __restrict__ wql,
    const float* __restrict__ w_proj, u16* __restrict__ wph, u16* __restrict__ wpl) {
  __shared__ float t[32][33];
  const int b = blockIdx.x;
  const int tid = threadIdx.x;

  if (b < 1536) {  // split8: fp32 -> bf16 hi/lo, 8 elem/thread
    const int i = b * 256 + tid;
    const float4* p4 = (const float4*)x;
    float4 a = p4[2 * i], c = p4[2 * i + 1];
    float v[8] = {a.x, a.y, a.z, a.w, c.x, c.y, c.z, c.w};
    u32 hw[4], lw[4];
#pragma unroll
    for (int j = 0; j < 4; ++j) {
      u16 h0 = f2bf(v[2 * j]), h1 = f2bf(v[2 * j + 1]);
      u16 l0 = f2bf(v[2 * j] - bf2f(h0)), l1 = f2bf(v[2 * j + 1] - bf2f(h1));
      hw[j] = (u32)h0 | ((u32)h1 << 16);
      lw[j] = (u32)l0 | ((u32)l1 << 16);
    }
    ((uint4*)xh)[i] = make_uint4(hw[0], hw[1], hw[2], hw[3]);
    ((uint4*)xl)[i] = make_uint4(lw[0], lw[1], lw[2], lw[3]);
    return;
  }

  // splitT: in [K][N] fp32 -> out [N][K] bf16 hi/lo
  const float* in;
  u16 *oh, *ol;
  int bx, by, N;
  if (b < 3264) {
    int bb = b - 1536;
    bx = bb % 72;
    by = bb / 72;
    in = w_qkv; oh = wqh; ol = wql; N = 2304;
  } else {
    int bb = b - 3264;
    bx = bb % 24;
    by = bb / 24;
    in = w_proj; oh = wph; ol = wpl; N = 768;
  }
  const int K = 768;
  const int n0 = bx * 32, k0 = by * 32;
  const int tx = tid & 31, ty = tid >> 5;
#pragma unroll
  for (int q = 0; q < 4; ++q)
    t[ty + 8 * q][tx] = in[(size_t)(k0 + ty + 8 * q) * N + n0 + tx];
  __syncthreads();
#pragma unroll
  for (int q = 0; q < 4; ++q) {
    float v = t[tx][ty + 8 * q];
    u16 h = f2bf(v);
    size_t oi = (size_t)(n0 + ty + 8 * q) * K + k0 + tx;
    oh[oi] = h;
    ol[oi] = f2bf(v - bf2f(h));
  }
}

// ---------------------------------------------------------------------------
// Coalesced V transpose: qkv V block [N][DH] -> vT [(b,h,d)][N] per head.
// ---------------------------------------------------------------------------
__global__ __launch_bounds__(256) void vtrans(const u16* __restrict__ qkvh,
                                              const u16* __restrict__ qkvl,
                                              u16* __restrict__ vth,
                                              u16* __restrict__ vtl) {
  __shared__ u16 th[4096], tl[4096];
  const int tid = threadIdx.x;
  const int kv0 = blockIdx.x * 64;
  const int hh = blockIdx.y, bb = blockIdx.z;
  const int sc8 = tid & 7, srow = tid >> 3;  // srow 0..31
#pragma unroll
  for (int q = 0; q < 2; ++q) {
    int row = q * 32 + srow;
    size_t ga = (size_t)(bb * 2048 + kv0 + row) * 2304 + 1536 + hh * 64 + sc8 * 8;
    *(uint4*)&th[SWZ(row, sc8 * 8)] = *(const uint4*)(qkvh + ga);
    *(uint4*)&tl[SWZ(row, sc8 * 8)] = *(const uint4*)(qkvl + ga);
  }
  __syncthreads();
#pragma unroll
  for (int q = 0; q < 2; ++q) {
    int d = q * 32 + srow;  // output row = head dim
    u32 hw[4], lw[4];
#pragma unroll
    for (int j = 0; j < 4; ++j) {
      int kv = sc8 * 8 + 2 * j;
      u16 h0 = th[SWZ(kv, d)], h1 = th[SWZ(kv + 1, d)];
      u16 l0 = tl[SWZ(kv, d)], l1 = tl[SWZ(kv + 1, d)];
      hw[j] = (u32)h0 | ((u32)h1 << 16);
      lw[j] = (u32)l0 | ((u32)l1 << 16);
    }
    size_t go = (size_t)((bb * 12 + hh) * 64 + d) * 2048 + kv0 + sc8 * 8;
    *(uint4*)(vth + go) = make_uint4(hw[0], hw[1], hw[2], hw[3]);
    *(uint4*)(vtl + go) = make_uint4(lw[0], lw[1], lw[2], lw[3]);
  }
}

// ---------------------------------------------------------------------------
// Split-bf16 GEMM (128x128 tile): qkv projection. Unchanged from R10.
// ---------------------------------------------------------------------------
__global__ __launch_bounds__(256, 3) void gemm_split(
    const u16* __restrict__ Ah, const u16* __restrict__ Al,
    const u16* __restrict__ BTh, const u16* __restrict__ BTl,
    u16* __restrict__ Ch, u16* __restrict__ Cl, int N, int K) {
  __shared__ u16 Ash[128 * 32], Asl[128 * 32], Bsh[128 * 32], Bsl[128 * 32];

  const int tid = threadIdx.x;
  const int wave = tid >> 6, lane = tid & 63;
  const int lr = lane & 15, lg = lane >> 4;
  const int wm = (wave >> 1) * 64, wn = (wave & 1) * 64;
  const int m0 = blockIdx.y * 128, n0 = blockIdx.x * 128;

  const int srow = wave * 16 + (lane >> 2);             // 0..63
  const int gc = ((lane & 3) ^ ((srow >> 1) & 3)) * 8;  // swizzled chunk (u16)

  const u16* gAh0 = Ah + (size_t)(m0 + srow) * K + gc;
  const u16* gAl0 = Al + (size_t)(m0 + srow) * K + gc;
  const u16* gBh0 = BTh + (size_t)(n0 + srow) * K + gc;
  const u16* gBl0 = BTl + (size_t)(n0 + srow) * K + gc;
  const size_t rstep = (size_t)64 * K;

  u16* lAh = &Ash[wave * 512];
  u16* lAl = &Asl[wave * 512];
  u16* lBh = &Bsh[wave * 512];
  u16* lBl = &Bsl[wave * 512];

  const f32x4 fz = {0.f, 0.f, 0.f, 0.f};
  f32x4 acc[4][4];
#pragma unroll
  for (int i = 0; i < 4; ++i)
#pragma unroll
    for (int j = 0; j < 4; ++j) acc[i][j] = fz;

  for (int k0 = 0; k0 < K; k0 += 32) {
    __syncthreads();
    gload16(gAh0 + k0, lAh);
    gload16(gAh0 + rstep + k0, lAh + 2048);
    gload16(gAl0 + k0, lAl);
    gload16(gAl0 + rstep + k0, lAl + 2048);
    gload16(gBh0 + k0, lBh);
    gload16(gBh0 + rstep + k0, lBh + 2048);
    gload16(gBl0 + k0, lBl);
    gload16(gBl0 + rstep + k0, lBl + 2048);
    __syncthreads();

    s16x8 a_h[4], a_l[4];
#pragma unroll
    for (int i = 0; i < 4; ++i) {
      const int ar = wm + i * 16 + lr;
      const int ao = ar * 32 + ((lg ^ ((ar >> 1) & 3)) * 8);
      a_h[i] = *(const s16x8*)&Ash[ao];
      a_l[i] = *(const s16x8*)&Asl[ao];
    }
    __builtin_amdgcn_s_setprio(1);
#pragma unroll
    for (int j = 0; j < 4; ++j) {
      const int br = wn + j * 16 + lr;
      const int bo = br * 32 + ((lg ^ ((br >> 1) & 3)) * 8);
      s16x8 b_h = *(const s16x8*)&Bsh[bo];
      s16x8 b_l = *(const s16x8*)&Bsl[bo];
#pragma unroll
      for (int i = 0; i < 4; ++i) {
        acc[i][j] = MFMA(a_h[i], b_h, acc[i][j]);
        acc[i][j] = MFMA(a_h[i], b_l, acc[i][j]);
        acc[i][j] = MFMA(a_l[i], b_h, acc[i][j]);
      }
    }
    __builtin_amdgcn_s_setprio(0);
  }

#pragma unroll
  for (int i = 0; i < 4; ++i)
#pragma unroll
    for (int r = 0; r < 4; ++r) {
      const int row = m0 + wm + i * 16 + lg * 4 + r;
#pragma unroll
      for (int j = 0; j < 4; ++j) {
        const int col = n0 + wn + j * 16 + lr;
        const float v = acc[i][j][r];
        u16 hh = f2bf(v);
        Ch[(size_t)row * N + col] = hh;
        Cl[(size_t)row * N + col] = f2bf(v - bf2f(hh));
      }
    }
}

// ---------------------------------------------------------------------------
// gemm64: 64x64-tile split-bf16 GEMM for the proj GEMM (fp32 out + bias).
// Grid 12x64 = 768 blocks = 3 blocks/CU (128-tile gave 192 blocks = 25% of
// the machine). 4 waves as 2x2 of 32x32; wave w stages plane w via gload16.
// Same k/product accumulation order as gemm_split -> bit-identical numerics.
// ---------------------------------------------------------------------------
__global__ __launch_bounds__(256, 4) void gemm64(
    const u16* __restrict__ Ah, const u16* __restrict__ Al,
    const u16* __restrict__ BTh, const u16* __restrict__ BTl,
    float* __restrict__ Cf, const float* __restrict__ bias, int N, int K) {
  __shared__ u16 S[4][2048];  // per plane: 64 rows x 32 u16 (4KB)

  const int tid = threadIdx.x;
  const int wave = tid >> 6, lane = tid & 63;
  const int lr = lane & 15, lg = lane >> 4;
  const int wm = (wave >> 1) * 32, wn = (wave & 1) * 32;
  const int m0 = blockIdx.y * 64, n0 = blockIdx.x * 64;

  // Staging: wave w stages plane w (0:Ah 1:Al 2:Bh 3:Bl), 4 issues x 16 rows.
  const u16* gp = (wave == 0) ? Ah : (wave == 1) ? Al : (wave == 2) ? BTh : BTl;
  const int rbase = (wave < 2) ? m0 : n0;
  const int r16 = lane >> 2;                              // row within 16
  const int gc = ((lane & 3) ^ ((lane >> 3) & 3)) * 8;    // swizzled chunk
  const u16* g0 = gp + (size_t)(rbase + r16) * K + gc;
  const u16* g1 = g0 + (size_t)16 * K;
  const u16* g2 = g0 + (size_t)32 * K;
  const u16* g3 = g0 + (size_t)48 * K;
  u16* ldst = S[wave];

  const f32x4 fz = {0.f, 0.f, 0.f, 0.f};
  f32x4 acc[2][2];
  acc[0][0] = fz; acc[0][1] = fz; acc[1][0] = fz; acc[1][1] = fz;

  for (int k0 = 0; k0 < K; k0 += 32) {
    __syncthreads();
    gload16(g0 + k0, ldst);
    gload16(g1 + k0, ldst + 512);
    gload16(g2 + k0, ldst + 1024);
    gload16(g3 + k0, ldst + 1536);
    __syncthreads();

    s16x8 a_h[2], a_l[2];
#pragma unroll
    for (int i = 0; i < 2; ++i) {
      const int ar = wm + i * 16 + lr;
      const int ao = ar * 32 + ((lg ^ ((ar >> 1) & 3)) * 8);
      a_h[i] = *(const s16x8*)&S[0][ao];
      a_l[i] = *(const s16x8*)&S[1][ao];
    }
    __builtin_amdgcn_s_setprio(1);
#pragma unroll
    for (int j = 0; j < 2; ++j) {
      const int br = wn + j * 16 + lr;
      const int bo = br * 32 + ((lg ^ ((br >> 1) & 3)) * 8);
      s16x8 b_h = *(const s16x8*)&S[2][bo];
      s16x8 b_l = *(const s16x8*)&S[3][bo];
#pragma unroll
      for (int i = 0; i < 2; ++i) {
        acc[i][j] = MFMA(a_h[i], b_h, acc[i][j]);
        acc[i][j] = MFMA(a_h[i], b_l, acc[i][j]);
        acc[i][j] = MFMA(a_l[i], b_h, acc[i][j]);
      }
    }
    __builtin_amdgcn_s_setprio(0);
  }

#pragma unroll
  for (int i = 0; i < 2; ++i)
#pragma unroll
    for (int r = 0; r < 4; ++r) {
      const int row = m0 + wm + i * 16 + lg * 4 + r;
#pragma unroll
      for (int j = 0; j < 2; ++j) {
        const int col = n0 + wn + j * 16 + lr;
        Cf[(size_t)row * N + col] = acc[i][j][r] + bias[col];
      }
    }
}

// ---------------------------------------------------------------------------
// Flash attention v4 (unchanged from R9/R10): KV-split=2, 8 waves, 128 q-rows,
// static-max softmax, fp32 partials + psum; bh->XCD locality grid.
// ---------------------------------------------------------------------------
__global__ __launch_bounds__(512, 4) void attn_split(
    const u16* __restrict__ qkvh, const u16* __restrict__ qkvl,
    const u16* __restrict__ vth, const u16* __restrict__ vtl,
    float* __restrict__ oP0, float* __restrict__ oP1,
    float* __restrict__ ps) {
  __shared__ u16 Ksh[4096], Ksl[4096], Vsh[4096], Vsl[4096];
  __shared__ u16 Ph[8][1024];

  const int tid = threadIdx.x;
  const int wave = tid >> 6, lane = tid & 63;
  const int lr = lane & 15, lg = lane >> 4;

  const int wgid = blockIdx.x;
  const int xcd = wgid & 7, t = wgid >> 3;
  const int hf = t & 1, qb = (t >> 1) & 15, g = t >> 5;
  const int bh = g * 8 + xcd;
  const int hh = bh % 12, bb = bh / 12;
  const int q0 = qb * 128;
  const int kbase = hf * 1024;
  const int sc8 = tid & 7, srow = tid >> 3;  // srow 0..63

  constexpr float SC2 = 0.18033688011f;  // 0.125 * log2(e)
  constexpr float M2 = 11.5415603267f;   // 8 * log2(e)

  s16x8 Qh[2], Ql[2];
  {
    const size_t qrow = (size_t)(bb * 2048 + q0 + wave * 16 + lr);
    const u16* qp = qkvh + qrow * 2304 + hh * 64;
    const u16* ql_ = qkvl + qrow * 2304 + hh * 64;
#pragma unroll
    for (int ks = 0; ks < 2; ++ks) {
      Qh[ks] = *(const s16x8*)(qp + ks * 32 + lg * 8);
      Ql[ks] = *(const s16x8*)(ql_ + ks * 32 + lg * 8);
    }
  }

  const f32x4 fz = {0.f, 0.f, 0.f, 0.f};
  f32x4 o[4] = {fz, fz, fz, fz};
  float psum[4] = {0.f, 0.f, 0.f, 0.f};

  uint4 kh, kl, vh, vl;
  auto loadc = [&](int kc) {
    const size_t gk = (size_t)(bb * 2048 + kc + srow) * 2304 + 768 + hh * 64 + sc8 * 8;
    const size_t gv = (size_t)((bb * 12 + hh) * 64 + srow) * 2048 + kc + sc8 * 8;
    kh = *(const uint4*)(qkvh + gk);
    kl = *(const uint4*)(qkvl + gk);
    vh = *(const uint4*)(vth + gv);
    vl = *(const uint4*)(vtl + gv);
  };
  loadc(kbase);

  for (int kc = kbase; kc < kbase + 1024; kc += 64) {
    __syncthreads();
    {
      const int li = SWZ(srow, sc8 * 8);
      *(uint4*)&Ksh[li] = kh;
      *(uint4*)&Ksl[li] = kl;
      *(uint4*)&Vsh[li] = vh;
      *(uint4*)&Vsl[li] = vl;
    }
    __syncthreads();
    if (kc + 64 < kbase + 1024) loadc(kc + 64);

    f32x4 s[4];
    __builtin_amdgcn_s_setprio(1);
#pragma unroll
    for (int f = 0; f < 4; ++f) {
      s[f] = fz;
#pragma unroll
      for (int ks = 0; ks < 2; ++ks) {
        s16x8 kbh = *(const s16x8*)&Ksh[SWZ(f * 16 + lr, ks * 32 + lg * 8)];
        s16x8 kbl = *(const s16x8*)&Ksl[SWZ(f * 16 + lr, ks * 32 + lg * 8)];
        s[f] = MFMA(Qh[ks], kbh, s[f]);
        s[f] = MFMA(Qh[ks], kbl, s[f]);
        s[f] = MFMA(Ql[ks], kbh, s[f]);
      }
    }
    __builtin_amdgcn_s_setprio(0);

#pragma unroll
    for (int f = 0; f < 4; ++f)
#pragma unroll
      for (int r = 0; r < 4; ++r) {
        float pv = exp2f(fmaf(s[f][r], SC2, -M2));
        u16 p_h = f2bf(pv);
        psum[r] += bf2f(p_h);
        Ph[wave][SWZ(lg * 4 + r, f * 16 + lr)] = p_h;
      }

    s16x8 pah[2];
#pragma unroll
    for (int ks = 0; ks < 2; ++ks)
      pah[ks] = *(const s16x8*)&Ph[wave][SWZ(lr, ks * 32 + lg * 8)];
    __builtin_amdgcn_s_setprio(1);
#pragma unroll
    for (int nf = 0; nf < 4; ++nf) {
#pragma unroll
      for (int ks = 0; ks < 2; ++ks) {
        s16x8 vbh = *(const s16x8*)&Vsh[SWZ(nf * 16 + lr, ks * 32 + lg * 8)];
        s16x8 vbl = *(const s16x8*)&Vsl[SWZ(nf * 16 + lr, ks * 32 + lg * 8)];
        o[nf] = MFMA(pah[ks], vbh, o[nf]);
        o[nf] = MFMA(pah[ks], vbl, o[nf]);
      }
    }
    __builtin_amdgcn_s_setprio(0);
  }

#pragma unroll
  for (int msk = 1; msk < 16; msk <<= 1)
#pragma unroll
    for (int r = 0; r < 4; ++r)
      psum[r] += __shfl_xor(psum[r], msk, 64);

  float* op = hf ? oP1 : oP0;
#pragma unroll
  for (int r = 0; r < 4; ++r) {
    const int row = bb * 2048 + q0 + wave * 16 + lg * 4 + r;
#pragma unroll
    for (int nf = 0; nf < 4; ++nf)
      op[(size_t)row * 768 + hh * 64 + nf * 16 + lr] = o[nf][r];
  }
  if (lr == 0) {
#pragma unroll
    for (int r = 0; r < 4; ++r)
      ps[hf * 49152 + bh * 2048 + q0 + wave * 16 + lg * 4 + r] = psum[r];
  }
}

// ---------------------------------------------------------------------------
// Combine: ao = (o0 + o1) * gate / (p0 + p1), written as bf16 hi/lo pair.
// ---------------------------------------------------------------------------
__global__ __launch_bounds__(256) void combine(
    const float* __restrict__ o0, const float* __restrict__ o1,
    const float* __restrict__ ps, const float* __restrict__ gate,
    u16* __restrict__ aoh, u16* __restrict__ aol) {
  const int i = blockIdx.x * 256 + threadIdx.x;
  if (i >= 4096 * 768 / 8) return;
  const int base = i * 8;
  const int row = base / 768, c0 = base % 768;
  const int hh = c0 >> 6;
  const int bb = row >> 11, n = row & 2047;
  const int bh = bb * 12 + hh;
  const float p = ps[bh * 2048 + n] + ps[49152 + bh * 2048 + n];
  const float inv = gate[hh] / p;
  float4 a0 = *(const float4*)(o0 + base);
  float4 a1 = *(const float4*)(o0 + base + 4);
  float4 b0 = *(const float4*)(o1 + base);
  float4 b1 = *(const float4*)(o1 + base + 4);
  float v[8] = {(a0.x + b0.x) * inv, (a0.y + b0.y) * inv,
                (a0.z + b0.z) * inv, (a0.w + b0.w) * inv,
                (a1.x + b1.x) * inv, (a1.y + b1.y) * inv,
                (a1.z + b1.z) * inv, (a1.w + b1.w) * inv};
  u32 hw[4], lw[4];
#pragma unroll
  for (int j = 0; j < 4; ++j) {
    u16 h0 = f2bf(v[2 * j]), h1 = f2bf(v[2 * j + 1]);
    u16 l0 = f2bf(v[2 * j] - bf2f(h0)), l1 = f2bf(v[2 * j + 1] - bf2f(h1));
    hw[j] = (u32)h0 | ((u32)h1 << 16);
    lw[j] = (u32)l0 | ((u32)l1 << 16);
  }
  *(uint4*)(aoh + base) = make_uint4(hw[0], hw[1], hw[2], hw[3]);
  *(uint4*)(aol + base) = make_uint4(lw[0], lw[1], lw[2], lw[3]);
}

// ---------------------------------------------------------------------------
extern "C" void kernel_launch(void* const* d_in, const int* in_sizes, int n_in,
                              void* d_out, int out_size, void* d_ws, size_t ws_size,
                              hipStream_t stream) {
  const float* x = (const float*)d_in[0];
  const float* w_qkv = (const float*)d_in[1];
  const float* gate = (const float*)d_in[2];
  const float* w_proj = (const float*)d_in[3];
  const float* b_proj = (const float*)d_in[4];
  float* out = (float*)d_out;

  u16* p = (u16*)d_ws;
  u16* xh = p; p += (size_t)4096 * 768;
  u16* xl = p; p += (size_t)4096 * 768;
  u16* wqh = p; p += (size_t)2304 * 768;
  u16* wql = p; p += (size_t)2304 * 768;
  u16* wph = p; p += (size_t)768 * 768;
  u16* wpl = p; p += (size_t)768 * 768;
  u16* qh = p; p += (size_t)4096 * 2304;
  u16* ql = p; p += (size_t)4096 * 2304;
  u16* vth = p; p += (size_t)24 * 64 * 2048;
  u16* vtl = p; p += (size_t)24 * 64 * 2048;
  u16* aoh = p; p += (size_t)4096 * 768;
  u16* aol = p; p += (size_t)4096 * 768;
  float* oP1 = (float*)p;  p += (size_t)2 * 4096 * 768;
  // Reused regions (dead by the time attn runs):
  float* oP0 = (float*)xh;   // over xh+xl
  float* ps  = (float*)wqh;  // over wqh

  prep<<<dim3(3840), dim3(256), 0, stream>>>(x, xh, xl, w_qkv, wqh, wql,
                                             w_proj, wph, wpl);

  gemm_split<<<dim3(2304 / 128, 4096 / 128), dim3(256), 0, stream>>>(
      xh, xl, wqh, wql, qh, ql, 2304, 768);

  vtrans<<<dim3(32, 12, 2), dim3(256), 0, stream>>>(qh, ql, vth, vtl);

  attn_split<<<dim3(768), dim3(512), 0, stream>>>(qh, ql, vth, vtl, oP0, oP1, ps);

  combine<<<dim3(1536), dim3(256), 0, stream>>>(oP0, oP1, ps, gate, aoh, aol);

  gemm64<<<dim3(768 / 64, 4096 / 64), dim3(256), 0, stream>>>(
      aoh, aol, wph, wpl, out, b_proj, 768, 768);
}